// Round 13
// baseline (295.067 us; speedup 1.0000x reference)
//
#include <hip/hip_runtime.h>

typedef __bf16 bf16;
typedef __attribute__((ext_vector_type(8))) __bf16 bf16x8;
typedef __attribute__((ext_vector_type(4))) __bf16 bf16x4;
typedef __attribute__((ext_vector_type(4))) float f32x4;

namespace {
constexpr int Bn = 2;
constexpr int T  = 16384;
constexpr int NL = 24;
constexpr int VOC = 259;
}

#define MFMA_B16(a, b, c) __builtin_amdgcn_mfma_f32_16x16x32_bf16((a), (b), (c), 0, 0, 0)

// async global->LDS 16B (wave-uniform LDS base + lane*16; per-lane global src)
__device__ __forceinline__ void gload_lds16(const void* g, void* l) {
  __builtin_amdgcn_global_load_lds((const __attribute__((address_space(1))) void*)g,
                                   (__attribute__((address_space(3))) void*)l, 16, 0, 0);
}

// ---------- prep: all weight reformats in one kernel ----------
__global__ void prep_all_k(const float* __restrict__ cw, const float* __restrict__ dw,
                           const float* __restrict__ fc1w, const float* __restrict__ encw,
                           const float* __restrict__ emb, const float* __restrict__ fc2w,
                           bf16* __restrict__ W2, bf16* __restrict__ fc1wb,
                           bf16* __restrict__ encwb, bf16* __restrict__ embb,
                           bf16* __restrict__ w2f) {
  const int tw = NL * 61440;
  const int n1 = 65536, n2 = 16384, n3 = 33152, n4 = 196608;
  int total = tw + n1 + n2 + n3 + n4;
  for (int idx = blockIdx.x * 256 + threadIdx.x; idx < total; idx += gridDim.x * 256) {
    if (idx < tw) {
      int l = idx / 61440; int r = idx % 61440;
      int s = r >> 12; int of = (r >> 9) & 7; int lane = (r >> 3) & 63; int j = r & 7;
      int o = of * 16 + (lane & 15);
      int kk = (lane >> 4) * 8 + j;
      float v;
      if (s < 12) { int k = s >> 2; int c = (s & 3) * 32 + kk; v = cw[((l * 128 + o) * 128 + c) * 3 + k]; }
      else        { int cc = (s - 12) * 32 + kk; v = (cc < 80) ? dw[(l * 128 + o) * 80 + cc] : 0.f; }
      W2[idx] = (bf16)v;
    } else {
      int m = idx - tw;
      if (m < n1) { fc1wb[m] = (bf16)fc1w[m]; }
      else if (m < n1 + n2) { int i = m - n1; encwb[i] = (bf16)encw[i]; }
      else if (m < n1 + n2 + n3) { int i = m - n1 - n2; embb[i] = (bf16)emb[i]; }
      else {
        int r = m - n1 - n2 - n3;
        int s = r / 12288; int r2 = r % 12288;
        int ot = r2 >> 9; int lane = (r2 >> 3) & 63; int j = r2 & 7;
        int o = ot * 16 + (lane & 15);
        int f = s * 32 + (lane >> 4) * 8 + j;
        w2f[r] = (bf16)((o < VOC) ? fc2w[o * 512 + f] : 0.f);
      }
    }
  }
}

// ---------- fused 4-stage upsample: one block per (frame f, batch b) ----------
// Output t in [256f, 256f+256) depends only on input column c[b, :, f]
// (time upsampling is pure x4 replication per stage; conv mixes channels only).
// Writes cuT2 frag-tiled: cuT2[((b*1024+t/16)*3+cc/32)*512 + (((cc>>3)&3)*16+(t&15))*8 + (cc&7)].
__global__ __launch_bounds__(256) void ups_all_k(
    const float* __restrict__ c, const float* __restrict__ W,
    const float* __restrict__ B, bf16* __restrict__ cuT2) {
  __shared__ float s0[80];
  __shared__ float s1[320];    // [ch][4]
  __shared__ float s2[1280];   // [ch][16]
  __shared__ float s3[5120];   // [ch][64]
  const int f = blockIdx.x, b = blockIdx.y;
  const int tid = threadIdx.x;
  if (tid < 80) s0[tid] = c[(b * 80 + tid) * 64 + f];
  __syncthreads();
  {  // stage 1: -> [ch][4]
    float b0 = B[0];
    for (int i = tid; i < 320; i += 256) {
      int ch = i >> 2, j = i & 3;
      float acc = b0;
#pragma unroll
      for (int kh = 0; kh < 3; ++kh) {
        int hr = ch + 1 - kh;
        if (hr >= 0 && hr < 80) acc += s0[hr] * W[kh * 4 + j];
      }
      s1[i] = fmaxf(acc, 0.f);
    }
  }
  __syncthreads();
  {  // stage 2: -> [ch][16]
    float b1 = B[1];
    for (int i = tid; i < 1280; i += 256) {
      int ch = i >> 4, j2 = i & 15;
      float acc = b1;
#pragma unroll
      for (int kh = 0; kh < 3; ++kh) {
        int hr = ch + 1 - kh;
        if (hr >= 0 && hr < 80) acc += s1[hr * 4 + (j2 >> 2)] * W[12 + kh * 4 + (j2 & 3)];
      }
      s2[i] = fmaxf(acc, 0.f);
    }
  }
  __syncthreads();
  {  // stage 3: -> [ch][64]
    float b2 = B[2];
    for (int i = tid; i < 5120; i += 256) {
      int ch = i >> 6, j3 = i & 63;
      float acc = b2;
#pragma unroll
      for (int kh = 0; kh < 3; ++kh) {
        int hr = ch + 1 - kh;
        if (hr >= 0 && hr < 80) acc += s2[hr * 16 + (j3 >> 2)] * W[24 + kh * 4 + (j3 & 3)];
      }
      s3[i] = fmaxf(acc, 0.f);
    }
  }
  __syncthreads();
  {  // stage 4: -> cuT2 frag tiles (cc in [0,96), zero-pad cc >= 80)
    float b3 = B[3];
    for (int i = tid; i < 96 * 256; i += 256) {
      int cc = i >> 8, j4 = i & 255;
      float v = 0.f;
      if (cc < 80) {
        float acc = b3;
#pragma unroll
        for (int kh = 0; kh < 3; ++kh) {
          int hr = cc + 1 - kh;
          if (hr >= 0 && hr < 80) acc += s3[hr * 64 + (j4 >> 2)] * W[36 + kh * 4 + (j4 & 3)];
        }
        v = fmaxf(acc, 0.f);
      }
      int tile = f * 16 + (j4 >> 4);
      size_t addr = (((size_t)b * 1024 + tile) * 3 + (cc >> 5)) * 512 +
                    ((((cc >> 3) & 3) * 16 + (j4 & 15)) << 3) + (cc & 7);
      cuT2[addr] = (bf16)v;
    }
  }
}

// ---------- encode: h = relu(enc_w @ emb[x] + enc_b) -> hbt (b,t,128) via LDS bounce ----------
__global__ __launch_bounds__(256, 2) void encode_k(
    const int* __restrict__ x, const bf16* __restrict__ embb, const bf16* __restrict__ encwb,
    const float* __restrict__ encb, bf16* __restrict__ hbt) {
  __shared__ char Eb[16384];   // 64 rows x 256B, XOR-swizzled 16B slots
  int t0 = blockIdx.x * 64, b = blockIdx.y;
  int tid = threadIdx.x, lane = tid & 63, wid = tid >> 6, wr = wid >> 1, wc = wid & 1;
  int lr = lane & 15, lk = lane >> 4;
  int tb = t0 + wc * 32;
  int xi[2];
#pragma unroll
  for (int n = 0; n < 2; ++n) xi[n] = x[b * T + tb + n * 16 + lr];
  f32x4 acc[4][2] = {};
#pragma unroll
  for (int s = 0; s < 4; ++s) {
    bf16x8 a[4], bb[2];
#pragma unroll
    for (int m = 0; m < 4; ++m) a[m] = *(const bf16x8*)(encwb + (wr * 64 + m * 16 + lr) * 128 + s * 32 + lk * 8);
#pragma unroll
    for (int n = 0; n < 2; ++n) bb[n] = *(const bf16x8*)(embb + xi[n] * 128 + s * 32 + lk * 8);
#pragma unroll
    for (int m = 0; m < 4; ++m)
#pragma unroll
      for (int n = 0; n < 2; ++n) acc[m][n] = MFMA_B16(a[m], bb[n], acc[m][n]);
  }
#pragma unroll
  for (int m = 0; m < 4; ++m)
#pragma unroll
    for (int n = 0; n < 2; ++n) {
      int obase = wr * 64 + m * 16 + lk * 4;
      int row = wc * 32 + n * 16 + lr;
      bf16x4 p;
#pragma unroll
      for (int r = 0; r < 4; ++r) p[r] = (bf16)fmaxf(acc[m][n][r] + encb[obase + r], 0.f);
      int byteo = obase * 2;
      int slot = ((byteo >> 4) ^ (row & 7)) & 15;
      *(bf16x4*)(Eb + row * 256 + (slot << 4) + (byteo & 15)) = p;
    }
  __syncthreads();
  const size_t btb = (size_t)b * T;
  for (int u = tid; u < 1024; u += 256) {
    int row = u >> 4, slot = u & 15;
    uint4 v = *(const uint4*)(Eb + row * 256 + ((((slot) ^ (row & 7)) & 15) << 4));
    *(uint4*)(hbt + (btb + t0 + row) * 128 + slot * 8) = v;
  }
}

// ---------- one dilated conv+cond+residual layer over LDS buffers ----------
template <int D, int NF, int ESRC, int EDST>
__device__ __forceinline__ void qlayer(
    const char* __restrict__ SRC, char* __restrict__ DST,
    const bf16* __restrict__ W, const bf16* __restrict__ cuT2,
    size_t bt16, int t0, const float* __restrict__ cb, const float* __restrict__ dbv,
    int wid, int lane, int lr, int lk) {
  constexpr int NCH = (NF > 5) ? 2 : 1;
  constexpr int NC0 = (NF + NCH - 1) / NCH;
  const int ob = wid * 16 + lk * 4;
  const f32x4 cv = *(const f32x4*)(cb + ob);
  const f32x4 dv = *(const f32x4*)(dbv + ob);
  const int byteo = ob * 2, slot0 = byteo >> 4, wib = byteo & 15;
#pragma unroll
  for (int ch = 0; ch < NCH; ++ch) {
    const int fb = ch * NC0;
    f32x4 acc[NC0] = {};
#pragma unroll
    for (int s = 0; s < 12; ++s) {
      const int k = s >> 2, shift = (k - 2) * D, sb = (s & 3) * 4;
      bf16x8 a = *(const bf16x8*)(W + ((s * 8 + wid) * 64 + lane) * 8);
#pragma unroll
      for (int n = 0; n < NC0; ++n) {
        if (fb + n < NF) {
          int row = (fb + n) * 16 + (ESRC - EDST) + lr + shift;
          int slot = ((sb + lk) ^ (row & 7)) & 15;
          bf16x8 bb = *(const bf16x8*)(SRC + row * 256 + slot * 16);
          acc[n] = MFMA_B16(a, bb, acc[n]);
        }
      }
    }
#pragma unroll
    for (int n = 0; n < NC0; ++n)
#pragma unroll
      for (int r = 0; r < 4; ++r) acc[n][r] = fmaxf(acc[n][r] + cv[r], 0.f);
#pragma unroll
    for (int s = 12; s < 15; ++s) {
      bf16x8 a = *(const bf16x8*)(W + ((s * 8 + wid) * 64 + lane) * 8);
#pragma unroll
      for (int n = 0; n < NC0; ++n) {
        if (fb + n < NF) {
          int tb2 = t0 - EDST + (fb + n) * 16;
          int tile = (tb2 < 0 ? 0 : tb2) >> 4;
          bf16x8 bb = *(const bf16x8*)(cuT2 + ((bt16 + tile) * 3 + (s - 12)) * 512 + lane * 8);
          acc[n] = MFMA_B16(a, bb, acc[n]);
        }
      }
    }
#pragma unroll
    for (int n = 0; n < NC0; ++n) {
      if (fb + n < NF) {
        const int gn = fb + n;
        const int t = t0 - EDST + gn * 16 + lr;
        const int rowS = gn * 16 + (ESRC - EDST) + lr;
        const int slotS = (slot0 ^ (rowS & 7)) & 15;
        bf16x4 hb = *(const bf16x4*)(SRC + rowS * 256 + (slotS << 4) + wib);
        const int rb = gn * 16 + lr;
        bf16x4 p;
#pragma unroll
        for (int r = 0; r < 4; ++r) {
          float vv = fmaxf(acc[n][r] + dv[r] + (float)hb[r], 0.f);
          if (t < 0) vv = 0.f;
          p[r] = (bf16)vv;
        }
        *(bf16x4*)(DST + rb * 256 + (((slot0 ^ (rb & 7)) & 15) << 4) + wib) = p;
      }
    }
  }
}

// ---------- fused quad layer (dilations 1,2,4,8): one staging, 4 layers in LDS ----------
__global__ __launch_bounds__(512, 4) void layer4_k(
    const bf16* __restrict__ hbt_in, bf16* __restrict__ hbt_out,
    const bf16* __restrict__ W4, const bf16* __restrict__ cuT2,
    const float* __restrict__ cb, const float* __restrict__ db) {
  __shared__ uint4 B0u[128 * 16];
  __shared__ uint4 B1u[112 * 16];
  char* B0 = (char*)B0u;
  char* B1 = (char*)B1u;
  const int bx = blockIdx.x;
  const int tblk = ((bx & 7) << 5) | (bx >> 3);   // XCD-contiguous t ranges
  const int t0 = tblk * 64, b = blockIdx.y;
  const int tid = threadIdx.x, lane = tid & 63, wid = tid >> 6;
  const int lr = lane & 15, lk = lane >> 4;
  const size_t btb = (size_t)b * T;
  const size_t bt16 = (size_t)b * 1024;

  if (t0 >= 64) {
#pragma unroll
    for (int i = 0; i < 4; ++i) {
      int row0 = i * 32 + wid * 4;
      int row = row0 + (lane >> 4);
      int srcslot = (lane & 15) ^ (row & 7);
      gload_lds16(hbt_in + (btb + t0 - 64 + row) * 128 + srcslot * 8, B0 + row0 * 256);
    }
  } else {
    uint4 zv; zv.x = zv.y = zv.z = zv.w = 0;
    for (int u = tid; u < 128 * 16; u += 512) {
      int row = u >> 4, slot = u & 15;
      int t = t0 - 64 + row;
      uint4 v = (t >= 0) ? *(const uint4*)(hbt_in + (btb + t) * 128 + slot * 8) : zv;
      *(uint4*)(B0 + row * 256 + (((slot ^ (row & 7)) & 15) << 4)) = v;
    }
  }
  __syncthreads();
  qlayer<1, 7, 64, 48>(B0, B1, W4,             cuT2, bt16, t0, cb,       db,       wid, lane, lr, lk);
  __syncthreads();
  qlayer<2, 6, 48, 32>(B1, B0, W4 + 61440,     cuT2, bt16, t0, cb + 128, db + 128, wid, lane, lr, lk);
  __syncthreads();
  qlayer<4, 5, 32, 16>(B0, B1, W4 + 2 * 61440, cuT2, bt16, t0, cb + 256, db + 256, wid, lane, lr, lk);
  __syncthreads();
  qlayer<8, 4, 16, 0>(B1, B0, W4 + 3 * 61440,  cuT2, bt16, t0, cb + 384, db + 384, wid, lane, lr, lk);
  __syncthreads();
  for (int u = tid; u < 1024; u += 512) {
    int row = u >> 4, slot = u & 15;
    uint4 v = *(const uint4*)(B0 + row * 256 + (((slot ^ (row & 7)) & 15) << 4));
    *(uint4*)(hbt_out + (btb + t0 + row) * 128 + slot * 8) = v;
  }
}

// ---------- fused pair layer (d=16,32): one o-frag per wave ----------
template <int D1>
__global__ __launch_bounds__(512, 4) void layer2_k(
    const bf16* __restrict__ hbt_in, bf16* __restrict__ hbt_out,
    const bf16* __restrict__ W2, const bf16* __restrict__ cuT2,
    const float* __restrict__ cb1, const float* __restrict__ db1,
    const float* __restrict__ cb2, const float* __restrict__ db2) {
  constexpr int D2 = 2 * D1;
  constexpr int EXT = (D1 == 16) ? 64 : 16;
  constexpr int NMF = EXT / 16;
  constexpr int NF = NMF + 4;
  constexpr int NCH = (D1 == 16) ? 2 : 1;
  constexpr int NFC = NF / NCH;
  constexpr int AOFF = EXT + 2 * D1;
  constexpr int AR = 64 + AOFF;
  constexpr int BR = 64 + EXT;
  __shared__ uint4 Au[AR * 16];
  __shared__ uint4 Bu[BR * 16];
  char* AB = (char*)Au;
  char* BB = (char*)Bu;
  const int bx = blockIdx.x;
  const int tblk = ((bx & 7) << 5) | (bx >> 3);
  const int t0 = tblk * 64, b = blockIdx.y;
  const int tid = threadIdx.x, lane = tid & 63, wid = tid >> 6;
  const int lr = lane & 15, lk = lane >> 4;
  const size_t btb = (size_t)b * T;
  const size_t bt16 = (size_t)b * 1024;
  const bf16* Wa = W2;
  const bf16* Wb = W2 + 61440;

  if (t0 >= AOFF) {
#pragma unroll
    for (int i = 0; i < AR / 32; ++i) {
      int row0 = i * 32 + wid * 4;
      int row = row0 + (lane >> 4);
      int srcslot = (lane & 15) ^ (row & 7);
      gload_lds16(hbt_in + (btb + t0 - AOFF + row) * 128 + srcslot * 8, AB + row0 * 256);
    }
  } else {
    uint4 zv; zv.x = zv.y = zv.z = zv.w = 0;
    for (int u = tid; u < AR * 16; u += 512) {
      int row = u >> 4, slot = u & 15;
      int t = t0 - AOFF + row;
      uint4 v = (t >= 0) ? *(const uint4*)(hbt_in + (btb + t) * 128 + slot * 8) : zv;
      *(uint4*)(AB + row * 256 + (((slot ^ (row & 7)) & 15) << 4)) = v;
    }
  }
  __syncthreads();

  f32x4 hl[4];
  const int ob = wid * 16 + lk * 4;
  const f32x4 dv1 = *(const f32x4*)(db1 + ob);
  const int byteo = ob * 2, slot0 = byteo >> 4, wib = byteo & 15;
#pragma unroll
  for (int ch = 0; ch < NCH; ++ch) {
    const int fb = ch * NFC;
    f32x4 acc[NFC] = {};
#pragma unroll
    for (int s = 0; s < 12; ++s) {
      const int k = s >> 2, shift = (k - 2) * D1, sb = (s & 3) * 4;
      bf16x8 a = *(const bf16x8*)(Wa + ((s * 8 + wid) * 64 + lane) * 8);
#pragma unroll
      for (int n = 0; n < NFC; ++n) {
        int row = 2 * D1 + (fb + n) * 16 + lr + shift;
        int slot = ((sb + lk) ^ (row & 7)) & 15;
        bf16x8 bb = *(const bf16x8*)(AB + row * 256 + slot * 16);
        acc[n] = MFMA_B16(a, bb, acc[n]);
      }
    }
    {
      const f32x4 bv = *(const f32x4*)(cb1 + wid * 16 + lk * 4);
#pragma unroll
      for (int n = 0; n < NFC; ++n)
#pragma unroll
        for (int r = 0; r < 4; ++r) acc[n][r] = fmaxf(acc[n][r] + bv[r], 0.f);
    }
#pragma unroll
    for (int s = 12; s < 15; ++s) {
      bf16x8 a = *(const bf16x8*)(Wa + ((s * 8 + wid) * 64 + lane) * 8);
#pragma unroll
      for (int n = 0; n < NFC; ++n) {
        int tb2 = t0 - EXT + (fb + n) * 16;
        int tile = (tb2 < 0 ? 0 : tb2) >> 4;
        bf16x8 bb = *(const bf16x8*)(cuT2 + ((bt16 + tile) * 3 + (s - 12)) * 512 + lane * 8);
        acc[n] = MFMA_B16(a, bb, acc[n]);
      }
    }
#pragma unroll
    for (int n = 0; n < NFC; ++n) {
      const int gn = fb + n;
      const int t = t0 - EXT + gn * 16 + lr;
      const int rowA = 2 * D1 + gn * 16 + lr;
      const int slotA = (slot0 ^ (rowA & 7)) & 15;
      bf16x4 hb = *(const bf16x4*)(AB + rowA * 256 + (slotA << 4) + wib);
      bf16x4 p;
#pragma unroll
      for (int r = 0; r < 4; ++r) {
        float vv = fmaxf(acc[n][r] + dv1[r] + (float)hb[r], 0.f);
        if (t < 0) vv = 0.f;
        if (gn >= NMF) hl[gn - NMF][r] = vv;
        p[r] = (bf16)vv;
      }
      const int rb = gn * 16 + lr;
      *(bf16x4*)(BB + rb * 256 + (((slot0 ^ (rb & 7)) & 15) << 4) + wib) = p;
    }
  }
  __syncthreads();

  f32x4 a2[4] = {};
#pragma unroll
  for (int s = 0; s < 12; ++s) {
    const int k = s >> 2, shift = (k - 2) * D2, sb = (s & 3) * 4;
    bf16x8 a = *(const bf16x8*)(Wb + ((s * 8 + wid) * 64 + lane) * 8);
#pragma unroll
    for (int n = 0; n < 4; ++n) {
      int row = EXT + n * 16 + lr + shift;
      int slot = ((sb + lk) ^ (row & 7)) & 15;
      bf16x8 bb = *(const bf16x8*)(BB + row * 256 + slot * 16);
      a2[n] = MFMA_B16(a, bb, a2[n]);
    }
  }
  {
    const f32x4 bv = *(const f32x4*)(cb2 + wid * 16 + lk * 4);
#pragma unroll
    for (int n = 0; n < 4; ++n)
#pragma unroll
      for (int r = 0; r < 4; ++r) a2[n][r] = fmaxf(a2[n][r] + bv[r], 0.f);
  }
#pragma unroll
  for (int s = 12; s < 15; ++s) {
    bf16x8 a = *(const bf16x8*)(Wb + ((s * 8 + wid) * 64 + lane) * 8);
#pragma unroll
    for (int n = 0; n < 4; ++n) {
      int tile = (t0 + n * 16) >> 4;
      bf16x8 bb = *(const bf16x8*)(cuT2 + ((bt16 + tile) * 3 + (s - 12)) * 512 + lane * 8);
      a2[n] = MFMA_B16(a, bb, a2[n]);
    }
  }
  const f32x4 dv2 = *(const f32x4*)(db2 + ob);
#pragma unroll
  for (int n = 0; n < 4; ++n) {
    bf16x4 p;
#pragma unroll
    for (int r = 0; r < 4; ++r)
      p[r] = (bf16)fmaxf(a2[n][r] + dv2[r] + hl[n][r], 0.f);
    const int rb = n * 16 + lr;
    *(bf16x4*)(AB + rb * 256 + (((slot0 ^ (rb & 7)) & 15) << 4) + wib) = p;
  }
  __syncthreads();
  for (int u = tid; u < 1024; u += 512) {
    int row = u >> 4, slot = u & 15;
    uint4 v = *(const uint4*)(AB + row * 256 + (((slot ^ (row & 7)) & 15) << 4));
    *(uint4*)(hbt_out + (btb + t0 + row) * 128 + slot * 8) = v;
  }
}

// ---------- fc1: hbt -> a1 (relu), a1 stored frag-tiled for fc2 ----------
__global__ __launch_bounds__(512, 4) void fc1_k(
    const bf16* __restrict__ hbt, const bf16* __restrict__ fc1wb,
    const float* __restrict__ b1, bf16* __restrict__ a1f) {
  __shared__ char H[16384];
  int t0 = blockIdx.x * 64, b = blockIdx.y;
  int tid = threadIdx.x, lane = tid & 63, wid = tid >> 6;
  int lr = lane & 15, lk = lane >> 4;
  const size_t btb = (size_t)b * T;
#pragma unroll
  for (int i = 0; i < 2; ++i) {
    int row0 = i * 32 + wid * 4;
    int row = row0 + (lane >> 4);
    int srcslot = (lane & 15) ^ (row & 7);
    gload_lds16(hbt + (btb + t0 + row) * 128 + srcslot * 8, H + row0 * 256);
  }
  __syncthreads();
  int wf = wid >> 1, wc = wid & 1;
#pragma unroll
  for (int f0 = 0; f0 < 2; ++f0) {
    f32x4 acc[4][2] = {};
#pragma unroll
    for (int s = 0; s < 4; ++s) {
      bf16x8 a[4], bb[2];
#pragma unroll
      for (int m = 0; m < 4; ++m)
        a[m] = *(const bf16x8*)(fc1wb + (f0 * 256 + wf * 64 + m * 16 + lr) * 128 + s * 32 + lk * 8);
#pragma unroll
      for (int n = 0; n < 2; ++n) {
        int row = wc * 32 + n * 16 + lr;
        int slot = ((s * 4 + lk) ^ (row & 7)) & 15;
        bb[n] = *(const bf16x8*)(H + row * 256 + slot * 16);
      }
#pragma unroll
      for (int m = 0; m < 4; ++m)
#pragma unroll
        for (int n = 0; n < 2; ++n) acc[m][n] = MFMA_B16(a[m], bb[n], acc[m][n]);
    }
#pragma unroll
    for (int m = 0; m < 4; ++m) {
      int fb = f0 * 256 + wf * 64 + m * 16 + lk * 4;
      const f32x4 bv = *(const f32x4*)(b1 + fb);
      int lhi = (fb >> 3) & 3, j0 = fb & 7, s16 = fb >> 5;
#pragma unroll
      for (int n = 0; n < 2; ++n) {
        int t = t0 + wc * 32 + n * 16 + lr;
        bf16x4 p;
#pragma unroll
        for (int r = 0; r < 4; ++r) p[r] = (bf16)fmaxf(acc[m][n][r] + bv[r], 0.f);
        size_t addr = (((size_t)b * 1024 + (t >> 4)) * 16 + s16) * 512 + (lhi * 16 + (t & 15)) * 8 + j0;
        *(bf16x4*)(a1f + addr) = p;
      }
    }
  }
}

// ---------- fc2: out = a1 @ fc2_w + b2 ----------
__global__ __launch_bounds__(512, 4) void fc2_k(
    const bf16* __restrict__ a1f, const bf16* __restrict__ w2f,
    const float* __restrict__ b2, float* __restrict__ out) {
  int t0 = blockIdx.x * 64, b = blockIdx.y;
  int tid = threadIdx.x, lane = tid & 63, wid = tid >> 6;
  int lr = lane & 15, lk = lane >> 4;
  const size_t tb16 = (size_t)b * 1024 + (t0 >> 4);
  f32x4 acc[4][3] = {};
#pragma unroll 4
  for (int s = 0; s < 16; ++s) {
    bf16x8 a[4], bb[3];
#pragma unroll
    for (int mt = 0; mt < 4; ++mt)
      a[mt] = *(const bf16x8*)(a1f + ((tb16 + mt) * 16 + s) * 512 + lane * 8);
#pragma unroll
    for (int no = 0; no < 3; ++no)
      bb[no] = *(const bf16x8*)(w2f + ((s * 24 + wid * 3 + no) * 64 + lane) * 8);
#pragma unroll
    for (int mt = 0; mt < 4; ++mt)
#pragma unroll
      for (int no = 0; no < 3; ++no) acc[mt][no] = MFMA_B16(a[mt], bb[no], acc[mt][no]);
  }
#pragma unroll
  for (int mt = 0; mt < 4; ++mt)
#pragma unroll
    for (int no = 0; no < 3; ++no) {
      int o = (wid * 3 + no) * 16 + lr;
      if (o >= VOC) continue;
      float bias = b2[o];
#pragma unroll
      for (int r = 0; r < 4; ++r) {
        int tg = t0 + mt * 16 + lk * 4 + r;
        if (tg < T - 1) out[((size_t)b * (T - 1) + tg) * VOC + o] = acc[mt][no][r] + bias;
      }
    }
}

extern "C" void kernel_launch(void* const* d_in, const int* in_sizes, int n_in,
                              void* d_out, int out_size, void* d_ws, size_t ws_size,
                              hipStream_t stream) {
  const int*   x      = (const int*)d_in[0];
  const float* c      = (const float*)d_in[1];
  const float* emb    = (const float*)d_in[2];
  const float* enc_w  = (const float*)d_in[3];
  const float* enc_b  = (const float*)d_in[4];
  const float* conv_w = (const float*)d_in[5];
  const float* conv_b = (const float*)d_in[6];
  const float* cond_w = (const float*)d_in[7];
  const float* cond_b = (const float*)d_in[8];
  const float* fc1_w  = (const float*)d_in[9];
  const float* fc1_b  = (const float*)d_in[10];
  const float* fc2_w  = (const float*)d_in[11];
  const float* fc2_b  = (const float*)d_in[12];
  const float* ups_w  = (const float*)d_in[13];
  const float* ups_b  = (const float*)d_in[14];
  float* out = (float*)d_out;
  (void)in_sizes; (void)n_in; (void)out_size; (void)ws_size;

  char* w = (char*)d_ws;
  bf16* hbtA  = (bf16*)w;  w += 8388608;   // bf16 (b,t,128) ping
  bf16* hbtB  = (bf16*)w;  w += 8388608;   // pong
  bf16* cuT2  = (bf16*)w;  w += 6291456;   // bf16 frag-tiled (b,1024,3,512)
  bf16* W2    = (bf16*)w;  w += 2949120;
  bf16* fc1wb = (bf16*)w;  w += 131072;
  bf16* encwb = (bf16*)w;  w += 32768;
  bf16* embb  = (bf16*)w;  w += 66560;
  bf16* w2f   = (bf16*)w;  w += 393216;    // 24 o-tiles x 16 s x 64 lanes x 8
  bf16* a1f   = (bf16*)w;  w += 33554432;  // bf16 frag-tiled (b,1024,16,512)

  prep_all_k<<<dim3(3488), dim3(256), 0, stream>>>(conv_w, cond_w, fc1_w, enc_w, emb, fc2_w,
                                                   W2, fc1wb, encwb, embb, w2f);

  ups_all_k<<<dim3(64, Bn), dim3(256), 0, stream>>>(c, ups_w, ups_b, cuT2);

  encode_k<<<dim3(T / 64, Bn), dim3(256), 0, stream>>>(x, embb, encwb, enc_b, hbtA);

  bf16* hti = hbtA; bf16* hto = hbtB;
  dim3 g(T / 64, Bn);
  for (int st = 0; st < 4; ++st) {
    int l0 = st * 6;
    layer4_k<<<g, dim3(512), 0, stream>>>(hti, hto, W2 + (size_t)l0 * 61440, cuT2,
                                          conv_b + l0 * 128, cond_b + l0 * 128);
    { bf16* t1 = hti; hti = hto; hto = t1; }
    int lp = l0 + 4;
    layer2_k<16><<<g, dim3(512), 0, stream>>>(hti, hto, W2 + (size_t)lp * 61440, cuT2,
                                              conv_b + lp * 128, cond_b + lp * 128,
                                              conv_b + (lp + 1) * 128, cond_b + (lp + 1) * 128);
    { bf16* t1 = hti; hti = hto; hto = t1; }
  }

  fc1_k<<<dim3(T / 64, Bn), dim3(512), 0, stream>>>(hti, fc1wb, fc1_b, a1f);
  fc2_k<<<dim3(T / 64, Bn), dim3(512), 0, stream>>>(a1f, w2f, fc2_b, out);
}

// Round 14
// 289.326 us; speedup vs baseline: 1.0198x; 1.0198x over previous
//
#include <hip/hip_runtime.h>

typedef __bf16 bf16;
typedef __attribute__((ext_vector_type(8))) __bf16 bf16x8;
typedef __attribute__((ext_vector_type(4))) __bf16 bf16x4;
typedef __attribute__((ext_vector_type(4))) float f32x4;

namespace {
constexpr int Bn = 2;
constexpr int T  = 16384;
constexpr int NL = 24;
constexpr int VOC = 259;
}

#define MFMA_B16(a, b, c) __builtin_amdgcn_mfma_f32_16x16x32_bf16((a), (b), (c), 0, 0, 0)

// async global->LDS 16B (wave-uniform LDS base + lane*16; per-lane global src)
__device__ __forceinline__ void gload_lds16(const void* g, void* l) {
  __builtin_amdgcn_global_load_lds((const __attribute__((address_space(1))) void*)g,
                                   (__attribute__((address_space(3))) void*)l, 16, 0, 0);
}

// ---------- prep: all weight reformats in one kernel ----------
__global__ void prep_all_k(const float* __restrict__ cw, const float* __restrict__ dw,
                           const float* __restrict__ fc1w, const float* __restrict__ encw,
                           const float* __restrict__ emb, const float* __restrict__ fc2w,
                           bf16* __restrict__ W2, bf16* __restrict__ fc1wb,
                           bf16* __restrict__ encwb, bf16* __restrict__ embb,
                           bf16* __restrict__ w2f) {
  const int tw = NL * 61440;
  const int n1 = 65536, n2 = 16384, n3 = 33152, n4 = 196608;
  int total = tw + n1 + n2 + n3 + n4;
  for (int idx = blockIdx.x * 256 + threadIdx.x; idx < total; idx += gridDim.x * 256) {
    if (idx < tw) {
      int l = idx / 61440; int r = idx % 61440;
      int s = r >> 12; int of = (r >> 9) & 7; int lane = (r >> 3) & 63; int j = r & 7;
      int o = of * 16 + (lane & 15);
      int kk = (lane >> 4) * 8 + j;
      float v;
      if (s < 12) { int k = s >> 2; int c = (s & 3) * 32 + kk; v = cw[((l * 128 + o) * 128 + c) * 3 + k]; }
      else        { int cc = (s - 12) * 32 + kk; v = (cc < 80) ? dw[(l * 128 + o) * 80 + cc] : 0.f; }
      W2[idx] = (bf16)v;
    } else {
      int m = idx - tw;
      if (m < n1) { fc1wb[m] = (bf16)fc1w[m]; }
      else if (m < n1 + n2) { int i = m - n1; encwb[i] = (bf16)encw[i]; }
      else if (m < n1 + n2 + n3) { int i = m - n1 - n2; embb[i] = (bf16)emb[i]; }
      else {
        int r = m - n1 - n2 - n3;
        int s = r / 12288; int r2 = r % 12288;
        int ot = r2 >> 9; int lane = (r2 >> 3) & 63; int j = r2 & 7;
        int o = ot * 16 + (lane & 15);
        int f = s * 32 + (lane >> 4) * 8 + j;
        w2f[r] = (bf16)((o < VOC) ? fc2w[o * 512 + f] : 0.f);
      }
    }
  }
}

// ---------- fused 4-stage upsample: one block per (frame f, batch b) ----------
// Output t in [256f, 256f+256) depends only on input column c[b, :, f].
// Stage-4 emission iterates the LINEAR cuT2 offset of this (b,f) region
// (16 tiles x 3 sc x 512 = 24576 contiguous bf16) -> fully coalesced stores.
__global__ __launch_bounds__(256) void ups_all_k(
    const float* __restrict__ c, const float* __restrict__ W,
    const float* __restrict__ B, bf16* __restrict__ cuT2) {
  __shared__ float s0[80];
  __shared__ float s1[320];    // [ch][4]
  __shared__ float s2[1280];   // [ch][16]
  __shared__ float s3[5120];   // [ch][64]
  const int f = blockIdx.x, b = blockIdx.y;
  const int tid = threadIdx.x;
  if (tid < 80) s0[tid] = c[(b * 80 + tid) * 64 + f];
  __syncthreads();
  {  // stage 1: -> [ch][4]
    float b0 = B[0];
    for (int i = tid; i < 320; i += 256) {
      int ch = i >> 2, j = i & 3;
      float acc = b0;
#pragma unroll
      for (int kh = 0; kh < 3; ++kh) {
        int hr = ch + 1 - kh;
        if (hr >= 0 && hr < 80) acc += s0[hr] * W[kh * 4 + j];
      }
      s1[i] = fmaxf(acc, 0.f);
    }
  }
  __syncthreads();
  {  // stage 2: -> [ch][16]
    float b1 = B[1];
    for (int i = tid; i < 1280; i += 256) {
      int ch = i >> 4, j2 = i & 15;
      float acc = b1;
#pragma unroll
      for (int kh = 0; kh < 3; ++kh) {
        int hr = ch + 1 - kh;
        if (hr >= 0 && hr < 80) acc += s1[hr * 4 + (j2 >> 2)] * W[12 + kh * 4 + (j2 & 3)];
      }
      s2[i] = fmaxf(acc, 0.f);
    }
  }
  __syncthreads();
  {  // stage 3: -> [ch][64]
    float b2 = B[2];
    for (int i = tid; i < 5120; i += 256) {
      int ch = i >> 6, j3 = i & 63;
      float acc = b2;
#pragma unroll
      for (int kh = 0; kh < 3; ++kh) {
        int hr = ch + 1 - kh;
        if (hr >= 0 && hr < 80) acc += s2[hr * 16 + (j3 >> 2)] * W[24 + kh * 4 + (j3 & 3)];
      }
      s3[i] = fmaxf(acc, 0.f);
    }
  }
  __syncthreads();
  {  // stage 4: -> linear, coalesced stores into this (b,f) frag-tile region
    float b3 = B[3];
    bf16* dst = cuT2 + ((size_t)b * 1024 + (size_t)f * 16) * 3 * 512;
    for (int o = tid; o < 24576; o += 256) {
      int toff = o / 1536;            // tile within frame (0..15)
      int r = o - toff * 1536;
      int sc = r >> 9;                // cc group of 32
      int low = r & 511;
      int lane = low >> 3, j = low & 7;
      int lr = lane & 15, lk = lane >> 4;
      int tf = toff * 16 + lr;        // time within frame (0..255)
      int cc = sc * 32 + lk * 8 + j;
      float v = 0.f;
      if (cc < 80) {
        float acc = b3;
#pragma unroll
        for (int kh = 0; kh < 3; ++kh) {
          int hr = cc + 1 - kh;
          if (hr >= 0 && hr < 80) acc += s3[hr * 64 + (tf >> 2)] * W[36 + kh * 4 + (tf & 3)];
        }
        v = fmaxf(acc, 0.f);
      }
      dst[o] = (bf16)v;
    }
  }
}

// ---------- encode: h = relu(enc_w @ emb[x] + enc_b) -> hbt (b,t,128) via LDS bounce ----------
__global__ __launch_bounds__(256, 2) void encode_k(
    const int* __restrict__ x, const bf16* __restrict__ embb, const bf16* __restrict__ encwb,
    const float* __restrict__ encb, bf16* __restrict__ hbt) {
  __shared__ char Eb[16384];   // 64 rows x 256B, XOR-swizzled 16B slots
  int t0 = blockIdx.x * 64, b = blockIdx.y;
  int tid = threadIdx.x, lane = tid & 63, wid = tid >> 6, wr = wid >> 1, wc = wid & 1;
  int lr = lane & 15, lk = lane >> 4;
  int tb = t0 + wc * 32;
  int xi[2];
#pragma unroll
  for (int n = 0; n < 2; ++n) xi[n] = x[b * T + tb + n * 16 + lr];
  f32x4 acc[4][2] = {};
#pragma unroll
  for (int s = 0; s < 4; ++s) {
    bf16x8 a[4], bb[2];
#pragma unroll
    for (int m = 0; m < 4; ++m) a[m] = *(const bf16x8*)(encwb + (wr * 64 + m * 16 + lr) * 128 + s * 32 + lk * 8);
#pragma unroll
    for (int n = 0; n < 2; ++n) bb[n] = *(const bf16x8*)(embb + xi[n] * 128 + s * 32 + lk * 8);
#pragma unroll
    for (int m = 0; m < 4; ++m)
#pragma unroll
      for (int n = 0; n < 2; ++n) acc[m][n] = MFMA_B16(a[m], bb[n], acc[m][n]);
  }
#pragma unroll
  for (int m = 0; m < 4; ++m)
#pragma unroll
    for (int n = 0; n < 2; ++n) {
      int obase = wr * 64 + m * 16 + lk * 4;
      int row = wc * 32 + n * 16 + lr;
      bf16x4 p;
#pragma unroll
      for (int r = 0; r < 4; ++r) p[r] = (bf16)fmaxf(acc[m][n][r] + encb[obase + r], 0.f);
      int byteo = obase * 2;
      int slot = ((byteo >> 4) ^ (row & 7)) & 15;
      *(bf16x4*)(Eb + row * 256 + (slot << 4) + (byteo & 15)) = p;
    }
  __syncthreads();
  const size_t btb = (size_t)b * T;
  for (int u = tid; u < 1024; u += 256) {
    int row = u >> 4, slot = u & 15;
    uint4 v = *(const uint4*)(Eb + row * 256 + ((((slot) ^ (row & 7)) & 15) << 4));
    *(uint4*)(hbt + (btb + t0 + row) * 128 + slot * 8) = v;
  }
}

// ---------- one dilated conv+cond+residual layer over LDS buffers ----------
template <int D, int NF, int ESRC, int EDST>
__device__ __forceinline__ void qlayer(
    const char* __restrict__ SRC, char* __restrict__ DST,
    const bf16* __restrict__ W, const bf16* __restrict__ cuT2,
    size_t bt16, int t0, const float* __restrict__ cb, const float* __restrict__ dbv,
    int wid, int lane, int lr, int lk) {
  constexpr int NCH = (NF > 5) ? 2 : 1;
  constexpr int NC0 = (NF + NCH - 1) / NCH;
  const int ob = wid * 16 + lk * 4;
  const f32x4 cv = *(const f32x4*)(cb + ob);
  const f32x4 dv = *(const f32x4*)(dbv + ob);
  const int byteo = ob * 2, slot0 = byteo >> 4, wib = byteo & 15;
#pragma unroll
  for (int ch = 0; ch < NCH; ++ch) {
    const int fb = ch * NC0;
    f32x4 acc[NC0] = {};
#pragma unroll
    for (int s = 0; s < 12; ++s) {
      const int k = s >> 2, shift = (k - 2) * D, sb = (s & 3) * 4;
      bf16x8 a = *(const bf16x8*)(W + ((s * 8 + wid) * 64 + lane) * 8);
#pragma unroll
      for (int n = 0; n < NC0; ++n) {
        if (fb + n < NF) {
          int row = (fb + n) * 16 + (ESRC - EDST) + lr + shift;
          int slot = ((sb + lk) ^ (row & 7)) & 15;
          bf16x8 bb = *(const bf16x8*)(SRC + row * 256 + slot * 16);
          acc[n] = MFMA_B16(a, bb, acc[n]);
        }
      }
    }
#pragma unroll
    for (int n = 0; n < NC0; ++n)
#pragma unroll
      for (int r = 0; r < 4; ++r) acc[n][r] = fmaxf(acc[n][r] + cv[r], 0.f);
#pragma unroll
    for (int s = 12; s < 15; ++s) {
      bf16x8 a = *(const bf16x8*)(W + ((s * 8 + wid) * 64 + lane) * 8);
#pragma unroll
      for (int n = 0; n < NC0; ++n) {
        if (fb + n < NF) {
          int tb2 = t0 - EDST + (fb + n) * 16;
          int tile = (tb2 < 0 ? 0 : tb2) >> 4;
          bf16x8 bb = *(const bf16x8*)(cuT2 + ((bt16 + tile) * 3 + (s - 12)) * 512 + lane * 8);
          acc[n] = MFMA_B16(a, bb, acc[n]);
        }
      }
    }
#pragma unroll
    for (int n = 0; n < NC0; ++n) {
      if (fb + n < NF) {
        const int gn = fb + n;
        const int t = t0 - EDST + gn * 16 + lr;
        const int rowS = gn * 16 + (ESRC - EDST) + lr;
        const int slotS = (slot0 ^ (rowS & 7)) & 15;
        bf16x4 hb = *(const bf16x4*)(SRC + rowS * 256 + (slotS << 4) + wib);
        const int rb = gn * 16 + lr;
        bf16x4 p;
#pragma unroll
        for (int r = 0; r < 4; ++r) {
          float vv = fmaxf(acc[n][r] + dv[r] + (float)hb[r], 0.f);
          if (t < 0) vv = 0.f;
          p[r] = (bf16)vv;
        }
        *(bf16x4*)(DST + rb * 256 + (((slot0 ^ (rb & 7)) & 15) << 4) + wib) = p;
      }
    }
  }
}

// ---------- fused quad layer (dilations 1,2,4,8): one staging, 4 layers in LDS ----------
__global__ __launch_bounds__(512, 4) void layer4_k(
    const bf16* __restrict__ hbt_in, bf16* __restrict__ hbt_out,
    const bf16* __restrict__ W4, const bf16* __restrict__ cuT2,
    const float* __restrict__ cb, const float* __restrict__ db) {
  __shared__ uint4 B0u[128 * 16];
  __shared__ uint4 B1u[112 * 16];
  char* B0 = (char*)B0u;
  char* B1 = (char*)B1u;
  const int bx = blockIdx.x;
  const int tblk = ((bx & 7) << 5) | (bx >> 3);   // XCD-contiguous t ranges
  const int t0 = tblk * 64, b = blockIdx.y;
  const int tid = threadIdx.x, lane = tid & 63, wid = tid >> 6;
  const int lr = lane & 15, lk = lane >> 4;
  const size_t btb = (size_t)b * T;
  const size_t bt16 = (size_t)b * 1024;

  if (t0 >= 64) {
#pragma unroll
    for (int i = 0; i < 4; ++i) {
      int row0 = i * 32 + wid * 4;
      int row = row0 + (lane >> 4);
      int srcslot = (lane & 15) ^ (row & 7);
      gload_lds16(hbt_in + (btb + t0 - 64 + row) * 128 + srcslot * 8, B0 + row0 * 256);
    }
  } else {
    uint4 zv; zv.x = zv.y = zv.z = zv.w = 0;
    for (int u = tid; u < 128 * 16; u += 512) {
      int row = u >> 4, slot = u & 15;
      int t = t0 - 64 + row;
      uint4 v = (t >= 0) ? *(const uint4*)(hbt_in + (btb + t) * 128 + slot * 8) : zv;
      *(uint4*)(B0 + row * 256 + (((slot ^ (row & 7)) & 15) << 4)) = v;
    }
  }
  __syncthreads();
  qlayer<1, 7, 64, 48>(B0, B1, W4,             cuT2, bt16, t0, cb,       db,       wid, lane, lr, lk);
  __syncthreads();
  qlayer<2, 6, 48, 32>(B1, B0, W4 + 61440,     cuT2, bt16, t0, cb + 128, db + 128, wid, lane, lr, lk);
  __syncthreads();
  qlayer<4, 5, 32, 16>(B0, B1, W4 + 2 * 61440, cuT2, bt16, t0, cb + 256, db + 256, wid, lane, lr, lk);
  __syncthreads();
  qlayer<8, 4, 16, 0>(B1, B0, W4 + 3 * 61440,  cuT2, bt16, t0, cb + 384, db + 384, wid, lane, lr, lk);
  __syncthreads();
  for (int u = tid; u < 1024; u += 512) {
    int row = u >> 4, slot = u & 15;
    uint4 v = *(const uint4*)(B0 + row * 256 + (((slot ^ (row & 7)) & 15) << 4));
    *(uint4*)(hbt_out + (btb + t0 + row) * 128 + slot * 8) = v;
  }
}

// ---------- fused pair layer (d=16,32): one o-frag per wave ----------
template <int D1>
__global__ __launch_bounds__(512, 4) void layer2_k(
    const bf16* __restrict__ hbt_in, bf16* __restrict__ hbt_out,
    const bf16* __restrict__ W2, const bf16* __restrict__ cuT2,
    const float* __restrict__ cb1, const float* __restrict__ db1,
    const float* __restrict__ cb2, const float* __restrict__ db2) {
  constexpr int D2 = 2 * D1;
  constexpr int EXT = (D1 == 16) ? 64 : 16;
  constexpr int NMF = EXT / 16;
  constexpr int NF = NMF + 4;
  constexpr int NCH = (D1 == 16) ? 2 : 1;
  constexpr int NFC = NF / NCH;
  constexpr int AOFF = EXT + 2 * D1;
  constexpr int AR = 64 + AOFF;
  constexpr int BR = 64 + EXT;
  __shared__ uint4 Au[AR * 16];
  __shared__ uint4 Bu[BR * 16];
  char* AB = (char*)Au;
  char* BB = (char*)Bu;
  const int bx = blockIdx.x;
  const int tblk = ((bx & 7) << 5) | (bx >> 3);
  const int t0 = tblk * 64, b = blockIdx.y;
  const int tid = threadIdx.x, lane = tid & 63, wid = tid >> 6;
  const int lr = lane & 15, lk = lane >> 4;
  const size_t btb = (size_t)b * T;
  const size_t bt16 = (size_t)b * 1024;
  const bf16* Wa = W2;
  const bf16* Wb = W2 + 61440;

  if (t0 >= AOFF) {
#pragma unroll
    for (int i = 0; i < AR / 32; ++i) {
      int row0 = i * 32 + wid * 4;
      int row = row0 + (lane >> 4);
      int srcslot = (lane & 15) ^ (row & 7);
      gload_lds16(hbt_in + (btb + t0 - AOFF + row) * 128 + srcslot * 8, AB + row0 * 256);
    }
  } else {
    uint4 zv; zv.x = zv.y = zv.z = zv.w = 0;
    for (int u = tid; u < AR * 16; u += 512) {
      int row = u >> 4, slot = u & 15;
      int t = t0 - AOFF + row;
      uint4 v = (t >= 0) ? *(const uint4*)(hbt_in + (btb + t) * 128 + slot * 8) : zv;
      *(uint4*)(AB + row * 256 + (((slot ^ (row & 7)) & 15) << 4)) = v;
    }
  }
  __syncthreads();

  f32x4 hl[4];
  const int ob = wid * 16 + lk * 4;
  const f32x4 dv1 = *(const f32x4*)(db1 + ob);
  const int byteo = ob * 2, slot0 = byteo >> 4, wib = byteo & 15;
#pragma unroll
  for (int ch = 0; ch < NCH; ++ch) {
    const int fb = ch * NFC;
    f32x4 acc[NFC] = {};
#pragma unroll
    for (int s = 0; s < 12; ++s) {
      const int k = s >> 2, shift = (k - 2) * D1, sb = (s & 3) * 4;
      bf16x8 a = *(const bf16x8*)(Wa + ((s * 8 + wid) * 64 + lane) * 8);
#pragma unroll
      for (int n = 0; n < NFC; ++n) {
        int row = 2 * D1 + (fb + n) * 16 + lr + shift;
        int slot = ((sb + lk) ^ (row & 7)) & 15;
        bf16x8 bb = *(const bf16x8*)(AB + row * 256 + slot * 16);
        acc[n] = MFMA_B16(a, bb, acc[n]);
      }
    }
    {
      const f32x4 bv = *(const f32x4*)(cb1 + wid * 16 + lk * 4);
#pragma unroll
      for (int n = 0; n < NFC; ++n)
#pragma unroll
        for (int r = 0; r < 4; ++r) acc[n][r] = fmaxf(acc[n][r] + bv[r], 0.f);
    }
#pragma unroll
    for (int s = 12; s < 15; ++s) {
      bf16x8 a = *(const bf16x8*)(Wa + ((s * 8 + wid) * 64 + lane) * 8);
#pragma unroll
      for (int n = 0; n < NFC; ++n) {
        int tb2 = t0 - EXT + (fb + n) * 16;
        int tile = (tb2 < 0 ? 0 : tb2) >> 4;
        bf16x8 bb = *(const bf16x8*)(cuT2 + ((bt16 + tile) * 3 + (s - 12)) * 512 + lane * 8);
        acc[n] = MFMA_B16(a, bb, acc[n]);
      }
    }
#pragma unroll
    for (int n = 0; n < NFC; ++n) {
      const int gn = fb + n;
      const int t = t0 - EXT + gn * 16 + lr;
      const int rowA = 2 * D1 + gn * 16 + lr;
      const int slotA = (slot0 ^ (rowA & 7)) & 15;
      bf16x4 hb = *(const bf16x4*)(AB + rowA * 256 + (slotA << 4) + wib);
      bf16x4 p;
#pragma unroll
      for (int r = 0; r < 4; ++r) {
        float vv = fmaxf(acc[n][r] + dv1[r] + (float)hb[r], 0.f);
        if (t < 0) vv = 0.f;
        if (gn >= NMF) hl[gn - NMF][r] = vv;
        p[r] = (bf16)vv;
      }
      const int rb = gn * 16 + lr;
      *(bf16x4*)(BB + rb * 256 + (((slot0 ^ (rb & 7)) & 15) << 4) + wib) = p;
    }
  }
  __syncthreads();

  f32x4 a2[4] = {};
#pragma unroll
  for (int s = 0; s < 12; ++s) {
    const int k = s >> 2, shift = (k - 2) * D2, sb = (s & 3) * 4;
    bf16x8 a = *(const bf16x8*)(Wb + ((s * 8 + wid) * 64 + lane) * 8);
#pragma unroll
    for (int n = 0; n < 4; ++n) {
      int row = EXT + n * 16 + lr + shift;
      int slot = ((sb + lk) ^ (row & 7)) & 15;
      bf16x8 bb = *(const bf16x8*)(BB + row * 256 + slot * 16);
      a2[n] = MFMA_B16(a, bb, a2[n]);
    }
  }
  {
    const f32x4 bv = *(const f32x4*)(cb2 + wid * 16 + lk * 4);
#pragma unroll
    for (int n = 0; n < 4; ++n)
#pragma unroll
      for (int r = 0; r < 4; ++r) a2[n][r] = fmaxf(a2[n][r] + bv[r], 0.f);
  }
#pragma unroll
  for (int s = 12; s < 15; ++s) {
    bf16x8 a = *(const bf16x8*)(Wb + ((s * 8 + wid) * 64 + lane) * 8);
#pragma unroll
    for (int n = 0; n < 4; ++n) {
      int tile = (t0 + n * 16) >> 4;
      bf16x8 bb = *(const bf16x8*)(cuT2 + ((bt16 + tile) * 3 + (s - 12)) * 512 + lane * 8);
      a2[n] = MFMA_B16(a, bb, a2[n]);
    }
  }
  const f32x4 dv2 = *(const f32x4*)(db2 + ob);
#pragma unroll
  for (int n = 0; n < 4; ++n) {
    bf16x4 p;
#pragma unroll
    for (int r = 0; r < 4; ++r)
      p[r] = (bf16)fmaxf(a2[n][r] + dv2[r] + hl[n][r], 0.f);
    const int rb = n * 16 + lr;
    *(bf16x4*)(AB + rb * 256 + (((slot0 ^ (rb & 7)) & 15) << 4) + wib) = p;
  }
  __syncthreads();
  for (int u = tid; u < 1024; u += 512) {
    int row = u >> 4, slot = u & 15;
    uint4 v = *(const uint4*)(AB + row * 256 + (((slot ^ (row & 7)) & 15) << 4));
    *(uint4*)(hbt_out + (btb + t0 + row) * 128 + slot * 8) = v;
  }
}

// ---------- fc1: hbt -> a1 (relu), a1 stored frag-tiled for fc2 ----------
__global__ __launch_bounds__(512, 4) void fc1_k(
    const bf16* __restrict__ hbt, const bf16* __restrict__ fc1wb,
    const float* __restrict__ b1, bf16* __restrict__ a1f) {
  __shared__ char H[16384];
  int t0 = blockIdx.x * 64, b = blockIdx.y;
  int tid = threadIdx.x, lane = tid & 63, wid = tid >> 6;
  int lr = lane & 15, lk = lane >> 4;
  const size_t btb = (size_t)b * T;
#pragma unroll
  for (int i = 0; i < 2; ++i) {
    int row0 = i * 32 + wid * 4;
    int row = row0 + (lane >> 4);
    int srcslot = (lane & 15) ^ (row & 7);
    gload_lds16(hbt + (btb + t0 + row) * 128 + srcslot * 8, H + row0 * 256);
  }
  __syncthreads();
  int wf = wid >> 1, wc = wid & 1;
#pragma unroll
  for (int f0 = 0; f0 < 2; ++f0) {
    f32x4 acc[4][2] = {};
#pragma unroll
    for (int s = 0; s < 4; ++s) {
      bf16x8 a[4], bb[2];
#pragma unroll
      for (int m = 0; m < 4; ++m)
        a[m] = *(const bf16x8*)(fc1wb + (f0 * 256 + wf * 64 + m * 16 + lr) * 128 + s * 32 + lk * 8);
#pragma unroll
      for (int n = 0; n < 2; ++n) {
        int row = wc * 32 + n * 16 + lr;
        int slot = ((s * 4 + lk) ^ (row & 7)) & 15;
        bb[n] = *(const bf16x8*)(H + row * 256 + slot * 16);
      }
#pragma unroll
      for (int m = 0; m < 4; ++m)
#pragma unroll
        for (int n = 0; n < 2; ++n) acc[m][n] = MFMA_B16(a[m], bb[n], acc[m][n]);
    }
#pragma unroll
    for (int m = 0; m < 4; ++m) {
      int fb = f0 * 256 + wf * 64 + m * 16 + lk * 4;
      const f32x4 bv = *(const f32x4*)(b1 + fb);
      int lhi = (fb >> 3) & 3, j0 = fb & 7, s16 = fb >> 5;
#pragma unroll
      for (int n = 0; n < 2; ++n) {
        int t = t0 + wc * 32 + n * 16 + lr;
        bf16x4 p;
#pragma unroll
        for (int r = 0; r < 4; ++r) p[r] = (bf16)fmaxf(acc[m][n][r] + bv[r], 0.f);
        size_t addr = (((size_t)b * 1024 + (t >> 4)) * 16 + s16) * 512 + (lhi * 16 + (t & 15)) * 8 + j0;
        *(bf16x4*)(a1f + addr) = p;
      }
    }
  }
}

// ---------- fc2: out = a1 @ fc2_w + b2 ----------
__global__ __launch_bounds__(512, 4) void fc2_k(
    const bf16* __restrict__ a1f, const bf16* __restrict__ w2f,
    const float* __restrict__ b2, float* __restrict__ out) {
  int t0 = blockIdx.x * 64, b = blockIdx.y;
  int tid = threadIdx.x, lane = tid & 63, wid = tid >> 6;
  int lr = lane & 15, lk = lane >> 4;
  const size_t tb16 = (size_t)b * 1024 + (t0 >> 4);
  f32x4 acc[4][3] = {};
#pragma unroll 4
  for (int s = 0; s < 16; ++s) {
    bf16x8 a[4], bb[3];
#pragma unroll
    for (int mt = 0; mt < 4; ++mt)
      a[mt] = *(const bf16x8*)(a1f + ((tb16 + mt) * 16 + s) * 512 + lane * 8);
#pragma unroll
    for (int no = 0; no < 3; ++no)
      bb[no] = *(const bf16x8*)(w2f + ((s * 24 + wid * 3 + no) * 64 + lane) * 8);
#pragma unroll
    for (int mt = 0; mt < 4; ++mt)
#pragma unroll
      for (int no = 0; no < 3; ++no) acc[mt][no] = MFMA_B16(a[mt], bb[no], acc[mt][no]);
  }
#pragma unroll
  for (int mt = 0; mt < 4; ++mt)
#pragma unroll
    for (int no = 0; no < 3; ++no) {
      int o = (wid * 3 + no) * 16 + lr;
      if (o >= VOC) continue;
      float bias = b2[o];
#pragma unroll
      for (int r = 0; r < 4; ++r) {
        int tg = t0 + mt * 16 + lk * 4 + r;
        if (tg < T - 1) out[((size_t)b * (T - 1) + tg) * VOC + o] = acc[mt][no][r] + bias;
      }
    }
}

extern "C" void kernel_launch(void* const* d_in, const int* in_sizes, int n_in,
                              void* d_out, int out_size, void* d_ws, size_t ws_size,
                              hipStream_t stream) {
  const int*   x      = (const int*)d_in[0];
  const float* c      = (const float*)d_in[1];
  const float* emb    = (const float*)d_in[2];
  const float* enc_w  = (const float*)d_in[3];
  const float* enc_b  = (const float*)d_in[4];
  const float* conv_w = (const float*)d_in[5];
  const float* conv_b = (const float*)d_in[6];
  const float* cond_w = (const float*)d_in[7];
  const float* cond_b = (const float*)d_in[8];
  const float* fc1_w  = (const float*)d_in[9];
  const float* fc1_b  = (const float*)d_in[10];
  const float* fc2_w  = (const float*)d_in[11];
  const float* fc2_b  = (const float*)d_in[12];
  const float* ups_w  = (const float*)d_in[13];
  const float* ups_b  = (const float*)d_in[14];
  float* out = (float*)d_out;
  (void)in_sizes; (void)n_in; (void)out_size; (void)ws_size;

  char* w = (char*)d_ws;
  bf16* hbtA  = (bf16*)w;  w += 8388608;   // bf16 (b,t,128) ping
  bf16* hbtB  = (bf16*)w;  w += 8388608;   // pong
  bf16* cuT2  = (bf16*)w;  w += 6291456;   // bf16 frag-tiled (b,1024,3,512)
  bf16* W2    = (bf16*)w;  w += 2949120;
  bf16* fc1wb = (bf16*)w;  w += 131072;
  bf16* encwb = (bf16*)w;  w += 32768;
  bf16* embb  = (bf16*)w;  w += 66560;
  bf16* w2f   = (bf16*)w;  w += 393216;    // 24 o-tiles x 16 s x 64 lanes x 8
  bf16* a1f   = (bf16*)w;  w += 33554432;  // bf16 frag-tiled (b,1024,16,512)

  prep_all_k<<<dim3(3488), dim3(256), 0, stream>>>(conv_w, cond_w, fc1_w, enc_w, emb, fc2_w,
                                                   W2, fc1wb, encwb, embb, w2f);

  ups_all_k<<<dim3(64, Bn), dim3(256), 0, stream>>>(c, ups_w, ups_b, cuT2);

  encode_k<<<dim3(T / 64, Bn), dim3(256), 0, stream>>>(x, embb, encwb, enc_b, hbtA);

  bf16* hti = hbtA; bf16* hto = hbtB;
  dim3 g(T / 64, Bn);
  for (int st = 0; st < 4; ++st) {
    int l0 = st * 6;
    layer4_k<<<g, dim3(512), 0, stream>>>(hti, hto, W2 + (size_t)l0 * 61440, cuT2,
                                          conv_b + l0 * 128, cond_b + l0 * 128);
    { bf16* t1 = hti; hti = hto; hto = t1; }
    int lp = l0 + 4;
    layer2_k<16><<<g, dim3(512), 0, stream>>>(hti, hto, W2 + (size_t)lp * 61440, cuT2,
                                              conv_b + lp * 128, cond_b + lp * 128,
                                              conv_b + (lp + 1) * 128, cond_b + (lp + 1) * 128);
    { bf16* t1 = hti; hti = hto; hto = t1; }
  }

  fc1_k<<<dim3(T / 64, Bn), dim3(512), 0, stream>>>(hti, fc1wb, fc1_b, a1f);
  fc2_k<<<dim3(T / 64, Bn), dim3(512), 0, stream>>>(a1f, w2f, fc2_b, out);
}

// Round 15
// 276.738 us; speedup vs baseline: 1.0662x; 1.0455x over previous
//
#include <hip/hip_runtime.h>

typedef __bf16 bf16;
typedef __attribute__((ext_vector_type(8))) __bf16 bf16x8;
typedef __attribute__((ext_vector_type(4))) __bf16 bf16x4;
typedef __attribute__((ext_vector_type(4))) float f32x4;

namespace {
constexpr int Bn = 2;
constexpr int T  = 16384;
constexpr int NL = 24;
constexpr int VOC = 259;
}

#define MFMA_B16(a, b, c) __builtin_amdgcn_mfma_f32_16x16x32_bf16((a), (b), (c), 0, 0, 0)

// ---------- prep: conv+cond weights, frag-ordered ----------
__global__ void prep_wconv_k(const float* __restrict__ cw, const float* __restrict__ dw,
                             bf16* __restrict__ W2) {
  int total = NL * 61440;
  for (int idx = blockIdx.x * 256 + threadIdx.x; idx < total; idx += gridDim.x * 256) {
    int l = idx / 61440; int r = idx % 61440;
    int s = r >> 12; int of = (r >> 9) & 7; int lane = (r >> 3) & 63; int j = r & 7;
    int o = of * 16 + (lane & 15);
    int kk = (lane >> 4) * 8 + j;
    float v;
    if (s < 12) { int k = s >> 2; int c = (s & 3) * 32 + kk; v = cw[((l * 128 + o) * 128 + c) * 3 + k]; }
    else        { int cc = (s - 12) * 32 + kk; v = (cc < 80) ? dw[(l * 128 + o) * 80 + cc] : 0.f; }
    W2[idx] = (bf16)v;
  }
}

// ---------- prep: fc1 / enc / emb bf16 copies + fc2 B-frag order (24 o-tiles) ----------
__global__ void prep_misc_k(const float* __restrict__ fc1w, const float* __restrict__ encw,
                            const float* __restrict__ emb, const float* __restrict__ fc2w,
                            bf16* __restrict__ fc1wb, bf16* __restrict__ encwb,
                            bf16* __restrict__ embb, bf16* __restrict__ w2f) {
  const int n1 = 65536, n2 = 16384, n3 = 33152, n4 = 196608;
  int total = n1 + n2 + n3 + n4;
  for (int idx = blockIdx.x * 256 + threadIdx.x; idx < total; idx += gridDim.x * 256) {
    if (idx < n1) { fc1wb[idx] = (bf16)fc1w[idx]; }
    else if (idx < n1 + n2) { int i = idx - n1; encwb[i] = (bf16)encw[i]; }
    else if (idx < n1 + n2 + n3) { int i = idx - n1 - n2; embb[i] = (bf16)emb[i]; }
    else {
      int r = idx - n1 - n2 - n3;
      int s = r / 12288; int r2 = r % 12288;
      int ot = r2 >> 9; int lane = (r2 >> 3) & 63; int j = r2 & 7;
      int o = ot * 16 + (lane & 15);
      int f = s * 32 + (lane >> 4) * 8 + j;
      w2f[r] = (bf16)((o < VOC) ? fc2w[o * 512 + f] : 0.f);
    }
  }
}

// ---------- upsample stages 1..3 (f32) ----------
__global__ void ups_stage_k(const float* __restrict__ in, float* __restrict__ out,
                            const float* __restrict__ W, const float* __restrict__ bptr, int Win) {
  int Wout = Win * 4;
  int total = Bn * 80 * Wout;
  float bias = *bptr;
  for (int idx = blockIdx.x * 256 + threadIdx.x; idx < total; idx += gridDim.x * 256) {
    int w = idx % Wout; int rest = idx / Wout;
    int hrow = rest % 80; int b = rest / 80;
    int win = w >> 2; int kw = w & 3;
    float acc = bias;
#pragma unroll
    for (int kh = 0; kh < 3; ++kh) {
      int hr = hrow + 1 - kh;
      if (hr >= 0 && hr < 80) acc += in[(b * 80 + hr) * Win + win] * W[kh * 4 + kw];
    }
    out[idx] = fmaxf(acc, 0.f);
  }
}

// ---------- fused upsample stage 4 -> cuT2 in B-frag tiled layout ----------
// cuT2[((b*1024 + t/16)*3 + cc/32)*512 + lane*8 + j], lane = (cc%32/8)*16 + (t%16)
__global__ void ups4_cuT_k(const float* __restrict__ in, const float* __restrict__ W,
                           const float* __restrict__ bptr, bf16* __restrict__ cuT2) {
  int total = Bn * 1024 * 3 * 512;
  float bias = *bptr;
  for (int idx = blockIdx.x * 256 + threadIdx.x; idx < total; idx += gridDim.x * 256) {
    int low = idx & 511; int j = low & 7; int lane = low >> 3;
    int g = idx >> 9; int sc = g % 3; int gt = g / 3; int tile = gt & 1023; int b = gt >> 10;
    int lr = lane & 15, lk = lane >> 4;
    int t = tile * 16 + lr;
    int cc = sc * 32 + lk * 8 + j;
    float v = 0.f;
    if (cc < 80) {
      int win = t >> 2, kw = t & 3;
      float acc = bias;
#pragma unroll
      for (int kh = 0; kh < 3; ++kh) {
        int hr = cc + 1 - kh;
        if (hr >= 0 && hr < 80) acc += in[(b * 80 + hr) * 4096 + win] * W[kh * 4 + kw];
      }
      v = fmaxf(acc, 0.f);
    }
    cuT2[idx] = (bf16)v;
  }
}

// ---------- encode: h = relu(enc_w @ emb[x] + enc_b) -> hbt (b,t,128) via LDS bounce ----------
__global__ __launch_bounds__(256, 2) void encode_k(
    const int* __restrict__ x, const bf16* __restrict__ embb, const bf16* __restrict__ encwb,
    const float* __restrict__ encb, bf16* __restrict__ hbt) {
  __shared__ char Eb[16384];   // 64 rows x 256B, XOR-swizzled 16B slots
  int t0 = blockIdx.x * 64, b = blockIdx.y;
  int tid = threadIdx.x, lane = tid & 63, wid = tid >> 6, wr = wid >> 1, wc = wid & 1;
  int lr = lane & 15, lk = lane >> 4;
  int tb = t0 + wc * 32;
  int xi[2];
#pragma unroll
  for (int n = 0; n < 2; ++n) xi[n] = x[b * T + tb + n * 16 + lr];
  f32x4 acc[4][2] = {};
#pragma unroll
  for (int s = 0; s < 4; ++s) {
    bf16x8 a[4], bb[2];
#pragma unroll
    for (int m = 0; m < 4; ++m) a[m] = *(const bf16x8*)(encwb + (wr * 64 + m * 16 + lr) * 128 + s * 32 + lk * 8);
#pragma unroll
    for (int n = 0; n < 2; ++n) bb[n] = *(const bf16x8*)(embb + xi[n] * 128 + s * 32 + lk * 8);
#pragma unroll
    for (int m = 0; m < 4; ++m)
#pragma unroll
      for (int n = 0; n < 2; ++n) acc[m][n] = MFMA_B16(a[m], bb[n], acc[m][n]);
  }
#pragma unroll
  for (int m = 0; m < 4; ++m)
#pragma unroll
    for (int n = 0; n < 2; ++n) {
      int obase = wr * 64 + m * 16 + lk * 4;
      int row = wc * 32 + n * 16 + lr;
      bf16x4 p;
#pragma unroll
      for (int r = 0; r < 4; ++r) p[r] = (bf16)fmaxf(acc[m][n][r] + encb[obase + r], 0.f);
      int byteo = obase * 2;
      int slot = ((byteo >> 4) ^ (row & 7)) & 15;
      *(bf16x4*)(Eb + row * 256 + (slot << 4) + (byteo & 15)) = p;
    }
  __syncthreads();
  const size_t btb = (size_t)b * T;
  for (int u = tid; u < 1024; u += 256) {
    int row = u >> 4, slot = u & 15;
    uint4 v = *(const uint4*)(Eb + row * 256 + ((((slot) ^ (row & 7)) & 15) << 4));
    *(uint4*)(hbt + (btb + t0 + row) * 128 + slot * 8) = v;
  }
}

// ---------- one dilated conv+cond+residual layer over LDS buffers ----------
// Out frags gn=0..NF-1 at t_rel = -EDST + gn*16; conv input SRC physical row =
// gn*16 + (ESRC-EDST) + lr + shift; residual = SRC at same t (no shift).
// DST physical row = gn*16 + lr. All rows XOR-swizzled 16B slots (256B rows).
template <int D, int NF, int ESRC, int EDST>
__device__ __forceinline__ void qlayer(
    const char* __restrict__ SRC, char* __restrict__ DST,
    const bf16* __restrict__ W, const bf16* __restrict__ cuT2,
    size_t bt16, int t0, const float* __restrict__ cb, const float* __restrict__ dbv,
    int wid, int lane, int lr, int lk) {
  constexpr int NCH = (NF > 5) ? 2 : 1;
  constexpr int NC0 = (NF + NCH - 1) / NCH;
  const int ob = wid * 16 + lk * 4;
  const f32x4 cv = *(const f32x4*)(cb + ob);
  const f32x4 dv = *(const f32x4*)(dbv + ob);
  const int byteo = ob * 2, slot0 = byteo >> 4, wib = byteo & 15;
#pragma unroll
  for (int ch = 0; ch < NCH; ++ch) {
    const int fb = ch * NC0;
    f32x4 acc[NC0] = {};
#pragma unroll
    for (int s = 0; s < 12; ++s) {
      const int k = s >> 2, shift = (k - 2) * D, sb = (s & 3) * 4;
      bf16x8 a = *(const bf16x8*)(W + ((s * 8 + wid) * 64 + lane) * 8);
#pragma unroll
      for (int n = 0; n < NC0; ++n) {
        if (fb + n < NF) {
          int row = (fb + n) * 16 + (ESRC - EDST) + lr + shift;
          int slot = ((sb + lk) ^ (row & 7)) & 15;
          bf16x8 bb = *(const bf16x8*)(SRC + row * 256 + slot * 16);
          acc[n] = MFMA_B16(a, bb, acc[n]);
        }
      }
    }
#pragma unroll
    for (int n = 0; n < NC0; ++n)
#pragma unroll
      for (int r = 0; r < 4; ++r) acc[n][r] = fmaxf(acc[n][r] + cv[r], 0.f);
#pragma unroll
    for (int s = 12; s < 15; ++s) {
      bf16x8 a = *(const bf16x8*)(W + ((s * 8 + wid) * 64 + lane) * 8);
#pragma unroll
      for (int n = 0; n < NC0; ++n) {
        if (fb + n < NF) {
          int tb2 = t0 - EDST + (fb + n) * 16;
          int tile = (tb2 < 0 ? 0 : tb2) >> 4;
          bf16x8 bb = *(const bf16x8*)(cuT2 + ((bt16 + tile) * 3 + (s - 12)) * 512 + lane * 8);
          acc[n] = MFMA_B16(a, bb, acc[n]);
        }
      }
    }
#pragma unroll
    for (int n = 0; n < NC0; ++n) {
      if (fb + n < NF) {
        const int gn = fb + n;
        const int t = t0 - EDST + gn * 16 + lr;
        const int rowS = gn * 16 + (ESRC - EDST) + lr;
        const int slotS = (slot0 ^ (rowS & 7)) & 15;
        bf16x4 hb = *(const bf16x4*)(SRC + rowS * 256 + (slotS << 4) + wib);
        const int rb = gn * 16 + lr;
        bf16x4 p;
#pragma unroll
        for (int r = 0; r < 4; ++r) {
          float vv = fmaxf(acc[n][r] + dv[r] + (float)hb[r], 0.f);
          if (t < 0) vv = 0.f;
          p[r] = (bf16)vv;
        }
        *(bf16x4*)(DST + rb * 256 + (((slot0 ^ (rb & 7)) & 15) << 4) + wib) = p;
      }
    }
  }
}

// ---------- fused quad layer (dilations 1,2,4,8): one staging, 4 layers in LDS ----------
// B0 (128 rows): input [t0-64,t0+64) -> L2 out (96) -> L4 out (64, copy-out).
// B1 (112 rows): L1 out (112) -> L3 out (80).
__global__ __launch_bounds__(512, 4) void layer4_k(
    const bf16* __restrict__ hbt_in, bf16* __restrict__ hbt_out,
    const bf16* __restrict__ W4, const bf16* __restrict__ cuT2,
    const float* __restrict__ cb, const float* __restrict__ db) {
  __shared__ uint4 B0u[128 * 16];
  __shared__ uint4 B1u[112 * 16];
  char* B0 = (char*)B0u;
  char* B1 = (char*)B1u;
  const int bx = blockIdx.x;
  const int tblk = ((bx & 7) << 5) | (bx >> 3);   // XCD-contiguous t ranges
  const int t0 = tblk * 64, b = blockIdx.y;
  const int tid = threadIdx.x, lane = tid & 63, wid = tid >> 6;
  const int lr = lane & 15, lk = lane >> 4;
  const size_t btb = (size_t)b * T;
  const size_t bt16 = (size_t)b * 1024;

  // stage input rows [t0-64, t0+64) into B0
  uint4 zv; zv.x = zv.y = zv.z = zv.w = 0;
  for (int u = tid; u < 128 * 16; u += 512) {
    int row = u >> 4, slot = u & 15;
    int t = t0 - 64 + row;
    uint4 v = (t >= 0) ? *(const uint4*)(hbt_in + (btb + t) * 128 + slot * 8) : zv;
    *(uint4*)(B0 + row * 256 + (((slot ^ (row & 7)) & 15) << 4)) = v;
  }
  __syncthreads();
  qlayer<1, 7, 64, 48>(B0, B1, W4,             cuT2, bt16, t0, cb,       db,       wid, lane, lr, lk);
  __syncthreads();
  qlayer<2, 6, 48, 32>(B1, B0, W4 + 61440,     cuT2, bt16, t0, cb + 128, db + 128, wid, lane, lr, lk);
  __syncthreads();
  qlayer<4, 5, 32, 16>(B0, B1, W4 + 2 * 61440, cuT2, bt16, t0, cb + 256, db + 256, wid, lane, lr, lk);
  __syncthreads();
  qlayer<8, 4, 16, 0>(B1, B0, W4 + 3 * 61440,  cuT2, bt16, t0, cb + 384, db + 384, wid, lane, lr, lk);
  __syncthreads();
  for (int u = tid; u < 1024; u += 512) {
    int row = u >> 4, slot = u & 15;
    uint4 v = *(const uint4*)(B0 + row * 256 + (((slot ^ (row & 7)) & 15) << 4));
    *(uint4*)(hbt_out + (btb + t0 + row) * 128 + slot * 8) = v;
  }
}

// ---------- fused pair layer (champion R8): one o-frag per wave ----------
template <int D1>
__global__ __launch_bounds__(512, 4) void layer2_k(
    const bf16* __restrict__ hbt_in, bf16* __restrict__ hbt_out,
    const bf16* __restrict__ W2, const bf16* __restrict__ cuT2,
    const float* __restrict__ cb1, const float* __restrict__ db1,
    const float* __restrict__ cb2, const float* __restrict__ db2) {
  constexpr int D2 = 2 * D1;
  constexpr int EXT = (D1 == 16) ? 64 : 16;
  constexpr int NMF = EXT / 16;
  constexpr int NF = NMF + 4;
  constexpr int NCH = (D1 == 16) ? 2 : 1;
  constexpr int NFC = NF / NCH;
  constexpr int AOFF = EXT + 2 * D1;
  constexpr int AR = 64 + AOFF;
  constexpr int BR = 64 + EXT;
  __shared__ uint4 Au[AR * 16];
  __shared__ uint4 Bu[BR * 16];
  char* AB = (char*)Au;
  char* BB = (char*)Bu;
  const int bx = blockIdx.x;
  const int tblk = ((bx & 7) << 5) | (bx >> 3);
  const int t0 = tblk * 64, b = blockIdx.y;
  const int tid = threadIdx.x, lane = tid & 63, wid = tid >> 6;
  const int lr = lane & 15, lk = lane >> 4;
  const size_t btb = (size_t)b * T;
  const size_t bt16 = (size_t)b * 1024;
  const bf16* Wa = W2;
  const bf16* Wb = W2 + 61440;

  uint4 zv; zv.x = zv.y = zv.z = zv.w = 0;
  for (int u = tid; u < AR * 16; u += 512) {
    int row = u >> 4, slot = u & 15;
    int t = t0 - AOFF + row;
    uint4 v = (t >= 0) ? *(const uint4*)(hbt_in + (btb + t) * 128 + slot * 8) : zv;
    *(uint4*)(AB + row * 256 + (((slot ^ (row & 7)) & 15) << 4)) = v;
  }
  __syncthreads();

  f32x4 hl[4];
  const int ob = wid * 16 + lk * 4;
  const f32x4 dv1 = *(const f32x4*)(db1 + ob);
  const int byteo = ob * 2, slot0 = byteo >> 4, wib = byteo & 15;
#pragma unroll
  for (int ch = 0; ch < NCH; ++ch) {
    const int fb = ch * NFC;
    f32x4 acc[NFC] = {};
#pragma unroll
    for (int s = 0; s < 12; ++s) {
      const int k = s >> 2, shift = (k - 2) * D1, sb = (s & 3) * 4;
      bf16x8 a = *(const bf16x8*)(Wa + ((s * 8 + wid) * 64 + lane) * 8);
#pragma unroll
      for (int n = 0; n < NFC; ++n) {
        int row = 2 * D1 + (fb + n) * 16 + lr + shift;
        int slot = ((sb + lk) ^ (row & 7)) & 15;
        bf16x8 bb = *(const bf16x8*)(AB + row * 256 + slot * 16);
        acc[n] = MFMA_B16(a, bb, acc[n]);
      }
    }
    {
      const f32x4 bv = *(const f32x4*)(cb1 + wid * 16 + lk * 4);
#pragma unroll
      for (int n = 0; n < NFC; ++n)
#pragma unroll
        for (int r = 0; r < 4; ++r) acc[n][r] = fmaxf(acc[n][r] + bv[r], 0.f);
    }
#pragma unroll
    for (int s = 12; s < 15; ++s) {
      bf16x8 a = *(const bf16x8*)(Wa + ((s * 8 + wid) * 64 + lane) * 8);
#pragma unroll
      for (int n = 0; n < NFC; ++n) {
        int tb2 = t0 - EXT + (fb + n) * 16;
        int tile = (tb2 < 0 ? 0 : tb2) >> 4;
        bf16x8 bb = *(const bf16x8*)(cuT2 + ((bt16 + tile) * 3 + (s - 12)) * 512 + lane * 8);
        acc[n] = MFMA_B16(a, bb, acc[n]);
      }
    }
#pragma unroll
    for (int n = 0; n < NFC; ++n) {
      const int gn = fb + n;
      const int t = t0 - EXT + gn * 16 + lr;
      const int rowA = 2 * D1 + gn * 16 + lr;
      const int slotA = (slot0 ^ (rowA & 7)) & 15;
      bf16x4 hb = *(const bf16x4*)(AB + rowA * 256 + (slotA << 4) + wib);
      bf16x4 p;
#pragma unroll
      for (int r = 0; r < 4; ++r) {
        float vv = fmaxf(acc[n][r] + dv1[r] + (float)hb[r], 0.f);
        if (t < 0) vv = 0.f;
        if (gn >= NMF) hl[gn - NMF][r] = vv;
        p[r] = (bf16)vv;
      }
      const int rb = gn * 16 + lr;
      *(bf16x4*)(BB + rb * 256 + (((slot0 ^ (rb & 7)) & 15) << 4) + wib) = p;
    }
  }
  __syncthreads();

  f32x4 a2[4] = {};
#pragma unroll
  for (int s = 0; s < 12; ++s) {
    const int k = s >> 2, shift = (k - 2) * D2, sb = (s & 3) * 4;
    bf16x8 a = *(const bf16x8*)(Wb + ((s * 8 + wid) * 64 + lane) * 8);
#pragma unroll
    for (int n = 0; n < 4; ++n) {
      int row = EXT + n * 16 + lr + shift;
      int slot = ((sb + lk) ^ (row & 7)) & 15;
      bf16x8 bb = *(const bf16x8*)(BB + row * 256 + slot * 16);
      a2[n] = MFMA_B16(a, bb, a2[n]);
    }
  }
  {
    const f32x4 bv = *(const f32x4*)(cb2 + wid * 16 + lk * 4);
#pragma unroll
    for (int n = 0; n < 4; ++n)
#pragma unroll
      for (int r = 0; r < 4; ++r) a2[n][r] = fmaxf(a2[n][r] + bv[r], 0.f);
  }
#pragma unroll
  for (int s = 12; s < 15; ++s) {
    bf16x8 a = *(const bf16x8*)(Wb + ((s * 8 + wid) * 64 + lane) * 8);
#pragma unroll
    for (int n = 0; n < 4; ++n) {
      int tile = (t0 + n * 16) >> 4;
      bf16x8 bb = *(const bf16x8*)(cuT2 + ((bt16 + tile) * 3 + (s - 12)) * 512 + lane * 8);
      a2[n] = MFMA_B16(a, bb, a2[n]);
    }
  }
  const f32x4 dv2 = *(const f32x4*)(db2 + ob);
#pragma unroll
  for (int n = 0; n < 4; ++n) {
    bf16x4 p;
#pragma unroll
    for (int r = 0; r < 4; ++r)
      p[r] = (bf16)fmaxf(a2[n][r] + dv2[r] + hl[n][r], 0.f);
    const int rb = n * 16 + lr;
    *(bf16x4*)(AB + rb * 256 + (((slot0 ^ (rb & 7)) & 15) << 4) + wib) = p;
  }
  __syncthreads();
  for (int u = tid; u < 1024; u += 512) {
    int row = u >> 4, slot = u & 15;
    uint4 v = *(const uint4*)(AB + row * 256 + (((slot ^ (row & 7)) & 15) << 4));
    *(uint4*)(hbt_out + (btb + t0 + row) * 128 + slot * 8) = v;
  }
}

// ---------- fc1: hbt -> a1 (relu), a1 stored frag-tiled for fc2 ----------
__global__ __launch_bounds__(512, 4) void fc1_k(
    const bf16* __restrict__ hbt, const bf16* __restrict__ fc1wb,
    const float* __restrict__ b1, bf16* __restrict__ a1f) {
  __shared__ char H[16384];
  int t0 = blockIdx.x * 64, b = blockIdx.y;
  int tid = threadIdx.x, lane = tid & 63, wid = tid >> 6;
  int lr = lane & 15, lk = lane >> 4;
  const size_t btb = (size_t)b * T;
  for (int u = tid; u < 1024; u += 512) {
    int row = u >> 4, slot = u & 15;
    uint4 v = *(const uint4*)(hbt + (btb + t0 + row) * 128 + slot * 8);
    *(uint4*)(H + row * 256 + (((slot ^ (row & 7)) & 15) << 4)) = v;
  }
  __syncthreads();
  int wf = wid >> 1, wc = wid & 1;
#pragma unroll
  for (int f0 = 0; f0 < 2; ++f0) {
    f32x4 acc[4][2] = {};
#pragma unroll
    for (int s = 0; s < 4; ++s) {
      bf16x8 a[4], bb[2];
#pragma unroll
      for (int m = 0; m < 4; ++m)
        a[m] = *(const bf16x8*)(fc1wb + (f0 * 256 + wf * 64 + m * 16 + lr) * 128 + s * 32 + lk * 8);
#pragma unroll
      for (int n = 0; n < 2; ++n) {
        int row = wc * 32 + n * 16 + lr;
        int slot = ((s * 4 + lk) ^ (row & 7)) & 15;
        bb[n] = *(const bf16x8*)(H + row * 256 + slot * 16);
      }
#pragma unroll
      for (int m = 0; m < 4; ++m)
#pragma unroll
        for (int n = 0; n < 2; ++n) acc[m][n] = MFMA_B16(a[m], bb[n], acc[m][n]);
    }
#pragma unroll
    for (int m = 0; m < 4; ++m) {
      int fb = f0 * 256 + wf * 64 + m * 16 + lk * 4;
      const f32x4 bv = *(const f32x4*)(b1 + fb);
      int lhi = (fb >> 3) & 3, j0 = fb & 7, s16 = fb >> 5;
#pragma unroll
      for (int n = 0; n < 2; ++n) {
        int t = t0 + wc * 32 + n * 16 + lr;
        bf16x4 p;
#pragma unroll
        for (int r = 0; r < 4; ++r) p[r] = (bf16)fmaxf(acc[m][n][r] + bv[r], 0.f);
        size_t addr = (((size_t)b * 1024 + (t >> 4)) * 16 + s16) * 512 + (lhi * 16 + (t & 15)) * 8 + j0;
        *(bf16x4*)(a1f + addr) = p;
      }
    }
  }
}

// ---------- fc2: out = a1 @ fc2_w + b2 ----------
__global__ __launch_bounds__(512, 4) void fc2_k(
    const bf16* __restrict__ a1f, const bf16* __restrict__ w2f,
    const float* __restrict__ b2, float* __restrict__ out) {
  int t0 = blockIdx.x * 64, b = blockIdx.y;
  int tid = threadIdx.x, lane = tid & 63, wid = tid >> 6;
  int lr = lane & 15, lk = lane >> 4;
  const size_t tb16 = (size_t)b * 1024 + (t0 >> 4);
  f32x4 acc[4][3] = {};
#pragma unroll 4
  for (int s = 0; s < 16; ++s) {
    bf16x8 a[4], bb[3];
#pragma unroll
    for (int mt = 0; mt < 4; ++mt)
      a[mt] = *(const bf16x8*)(a1f + ((tb16 + mt) * 16 + s) * 512 + lane * 8);
#pragma unroll
    for (int no = 0; no < 3; ++no)
      bb[no] = *(const bf16x8*)(w2f + ((s * 24 + wid * 3 + no) * 64 + lane) * 8);
#pragma unroll
    for (int mt = 0; mt < 4; ++mt)
#pragma unroll
      for (int no = 0; no < 3; ++no) acc[mt][no] = MFMA_B16(a[mt], bb[no], acc[mt][no]);
  }
#pragma unroll
  for (int mt = 0; mt < 4; ++mt)
#pragma unroll
    for (int no = 0; no < 3; ++no) {
      int o = (wid * 3 + no) * 16 + lr;
      if (o >= VOC) continue;
      float bias = b2[o];
#pragma unroll
      for (int r = 0; r < 4; ++r) {
        int tg = t0 + mt * 16 + lk * 4 + r;
        if (tg < T - 1) out[((size_t)b * (T - 1) + tg) * VOC + o] = acc[mt][no][r] + bias;
      }
    }
}

extern "C" void kernel_launch(void* const* d_in, const int* in_sizes, int n_in,
                              void* d_out, int out_size, void* d_ws, size_t ws_size,
                              hipStream_t stream) {
  const int*   x      = (const int*)d_in[0];
  const float* c      = (const float*)d_in[1];
  const float* emb    = (const float*)d_in[2];
  const float* enc_w  = (const float*)d_in[3];
  const float* enc_b  = (const float*)d_in[4];
  const float* conv_w = (const float*)d_in[5];
  const float* conv_b = (const float*)d_in[6];
  const float* cond_w = (const float*)d_in[7];
  const float* cond_b = (const float*)d_in[8];
  const float* fc1_w  = (const float*)d_in[9];
  const float* fc1_b  = (const float*)d_in[10];
  const float* fc2_w  = (const float*)d_in[11];
  const float* fc2_b  = (const float*)d_in[12];
  const float* ups_w  = (const float*)d_in[13];
  const float* ups_b  = (const float*)d_in[14];
  float* out = (float*)d_out;
  (void)in_sizes; (void)n_in; (void)out_size; (void)ws_size;

  char* w = (char*)d_ws;
  bf16* hbtA  = (bf16*)w;  w += 8388608;   // bf16 (b,t,128) ping
  bf16* hbtB  = (bf16*)w;  w += 8388608;   // pong
  bf16* cuT2  = (bf16*)w;  w += 6291456;   // bf16 frag-tiled (b,1024,3,512)
  bf16* W2    = (bf16*)w;  w += 2949120;
  bf16* fc1wb = (bf16*)w;  w += 131072;
  bf16* encwb = (bf16*)w;  w += 32768;
  bf16* embb  = (bf16*)w;  w += 66560;
  bf16* w2f   = (bf16*)w;  w += 393216;    // 24 o-tiles x 16 s x 64 lanes x 8
  bf16* a1f   = (bf16*)w;  w += 33554432;  // bf16 frag-tiled (b,1024,16,512)
  float* u1   = (float*)w; w += 2621440;
  float* u2   = (float*)w; w += 655360;

  prep_wconv_k<<<dim3(2880), dim3(256), 0, stream>>>(conv_w, cond_w, W2);
  prep_misc_k<<<dim3(1218), dim3(256), 0, stream>>>(fc1_w, enc_w, emb, fc2_w, fc1wb, encwb, embb, w2f);

  ups_stage_k<<<dim3(160),  dim3(256), 0, stream>>>(c,  u1, ups_w + 0,  ups_b + 0, 64);
  ups_stage_k<<<dim3(640),  dim3(256), 0, stream>>>(u1, u2, ups_w + 12, ups_b + 1, 256);
  ups_stage_k<<<dim3(2560), dim3(256), 0, stream>>>(u2, u1, ups_w + 24, ups_b + 2, 1024);
  ups4_cuT_k<<<dim3(4096),  dim3(256), 0, stream>>>(u1, ups_w + 36, ups_b + 3, cuT2);

  encode_k<<<dim3(T / 64, Bn), dim3(256), 0, stream>>>(x, embb, encwb, enc_b, hbtA);

  bf16* hti = hbtA; bf16* hto = hbtB;
  dim3 g(T / 64, Bn);
  for (int st = 0; st < 4; ++st) {
    int l0 = st * 6;
    layer4_k<<<g, dim3(512), 0, stream>>>(hti, hto, W2 + (size_t)l0 * 61440, cuT2,
                                          conv_b + l0 * 128, cond_b + l0 * 128);
    { bf16* t1 = hti; hti = hto; hto = t1; }
    int lp = l0 + 4;
    layer2_k<16><<<g, dim3(512), 0, stream>>>(hti, hto, W2 + (size_t)lp * 61440, cuT2,
                                              conv_b + lp * 128, cond_b + lp * 128,
                                              conv_b + (lp + 1) * 128, cond_b + (lp + 1) * 128);
    { bf16* t1 = hti; hti = hto; hto = t1; }
  }

  fc1_k<<<dim3(T / 64, Bn), dim3(512), 0, stream>>>(hti, fc1wb, fc1_b, a1f);
  fc2_k<<<dim3(T / 64, Bn), dim3(512), 0, stream>>>(a1f, w2f, fc2_b, out);
}